// Round 15
// baseline (357.546 us; speedup 1.0000x reference)
//
#include <hip/hip_runtime.h>
#include <math.h>

// ---------------------------------------------------------------------------
// NequIP fused, round 14: G=4 for ss/vv/sv waves, now that the R11 spill is
// fully attributed to the vs-wave dynamic-index bug (fixed in R13).
//
// R13 post-mortem: unrolling the vs half-loop cleared the scratch spill
// (WRITE 156->20MB) and gave 258us. Remaining: LDS pipe ~120k cyc/CU is the
// largest single consumer. G=4 halves ss/vv/sv A ds_reads (block total
// 1024->640) and doubles per-kk MFMA:mem to 16:8. vs wave = R13 verbatim.
// Spill tripwire: WRITE_SIZE must stay ~20MB.
// ---------------------------------------------------------------------------

typedef __attribute__((ext_vector_type(8))) short s8v;    // 8 x bf16 (4 VGPR)
typedef __attribute__((ext_vector_type(4))) float f4v;    // 16x16 acc (4 f32)
typedef unsigned short ushort_t;
typedef unsigned int uint_t;

#define NTHR 256
#define TE 64

__device__ __forceinline__ ushort_t f2bf(float x) {
    uint_t u = __float_as_uint(x);
    u += 0x7fffu + ((u >> 16) & 1u);   // round-to-nearest-even
    return (ushort_t)(u >> 16);
}
__device__ __forceinline__ float bf2f(ushort_t v) {
    return __uint_as_float((uint_t)v << 16);
}

// blocks [0,256): W2 [256][1024] fp32 -> W2bf [1024][256] bf16 (transposed).
// blocks [256,...): histogram of edge_dst into counts.
__global__ void prep_kernel(const float* __restrict__ W2, ushort_t* __restrict__ W2bf,
                            const int* __restrict__ edst, int* __restrict__ counts, int E) {
    if (blockIdx.x < 256) {
        int idx = blockIdx.x * 256 + threadIdx.x;      // 65536 threads, 4 k each
        int n  = idx & 1023;
        int k4 = (idx >> 10) << 2;
        uint_t lo = (uint_t)f2bf(W2[(size_t)(k4 + 0) * 1024 + n]) |
                    ((uint_t)f2bf(W2[(size_t)(k4 + 1) * 1024 + n]) << 16);
        uint_t hi = (uint_t)f2bf(W2[(size_t)(k4 + 2) * 1024 + n]) |
                    ((uint_t)f2bf(W2[(size_t)(k4 + 3) * 1024 + n]) << 16);
        ((uint2*)W2bf)[(n * 256 + k4) >> 2] = make_uint2(lo, hi);
    } else {
        int i = (blockIdx.x - 256) * 256 + threadIdx.x;
        if (i < E) atomicAdd(&counts[edst[i]], 1);
    }
}

// 1 block, 1024 threads: exclusive scan of counts[N] -> offsets[N+1]
__global__ __launch_bounds__(1024)
void scan_kernel(const int* __restrict__ counts, int* __restrict__ offsets, int N) {
    __shared__ int sdata[1024];
    const int t = threadIdx.x;
    const int C = (N + 1023) / 1024;
    const int lo = t * C;
    const int hi = min(lo + C, N);
    int sum = 0;
    for (int i = lo; i < hi; ++i) sum += counts[i];
    sdata[t] = sum;
    __syncthreads();
    for (int s = 1; s < 1024; s <<= 1) {
        int v = (t >= s) ? sdata[t - s] : 0;
        __syncthreads();
        sdata[t] += v;
        __syncthreads();
    }
    int run = sdata[t] - sum;
    for (int i = lo; i < hi; ++i) { offsets[i] = run; run += counts[i]; }
    if (t == 1023) offsets[N] = run;
}

__global__ void fill_kernel(const int* __restrict__ edst,
                            const int* __restrict__ offsets,
                            int* __restrict__ cursor,
                            int* __restrict__ elist, int E) {
    int i = blockIdx.x * 256 + threadIdx.x;
    if (i < E) {
        int d = edst[i];
        int pos = offsets[d] + atomicAdd(&cursor[d], 1);
        elist[pos] = i;
    }
}

// ---------------- gather: one wave per node; F is bf16 ----------------
__global__ __launch_bounds__(256)
void gather_kernel(const ushort_t* __restrict__ F,
                   const int* __restrict__ offsets,
                   const int* __restrict__ elist,
                   float* __restrict__ out, int N) {
    const int lane = threadIdx.x & 63;
    const int node = (blockIdx.x * 256 + threadIdx.x) >> 6;
    if (node >= N) return;
    const int base = offsets[node];
    const int end  = offsets[node + 1];
    float acc = 0.f;
    for (int j0 = base; j0 < end; j0 += 64) {
        const int rem = min(64, end - j0);
        int myeid = (lane < rem) ? elist[j0 + lane] : 0;
        int j = 0;
        for (; j + 4 <= rem; j += 4) {
            const int a0 = __shfl(myeid, j    );
            const int a1 = __shfl(myeid, j + 1);
            const int a2 = __shfl(myeid, j + 2);
            const int a3 = __shfl(myeid, j + 3);
            const float r0 = bf2f(F[(size_t)a0 * 64 + lane]);
            const float r1 = bf2f(F[(size_t)a1 * 64 + lane]);
            const float r2 = bf2f(F[(size_t)a2 * 64 + lane]);
            const float r3 = bf2f(F[(size_t)a3 * 64 + lane]);
            acc += (r0 + r1) + (r2 + r3);
        }
        for (; j < rem; ++j) {
            const int a = __shfl(myeid, j);
            acc += bf2f(F[(size_t)a * 64 + lane]);
        }
    }
    out[(size_t)node * 64 + lane] = acc;
}

// ---------------- main fused edge kernel (256 thr, 4 waves) ----------------
__global__ __launch_bounds__(NTHR, 2)
void nequip_mfma(const float* __restrict__ nodef,
                 const float* __restrict__ eattr,
                 const float* __restrict__ eemb,
                 const float* __restrict__ W1,
                 const float* __restrict__ b1,
                 const ushort_t* __restrict__ W2bf,
                 const float* __restrict__ b2,
                 const int* __restrict__ esrc,
                 ushort_t* __restrict__ F,
                 int E, float CC)
{
    __shared__ __align__(16) ushort_t sAu[TE * 256];   // 32 KB h bf16, A-frag order
    __shared__ __align__(16) float sB2[1024];          // 4 KB
    __shared__ __align__(16) float sEmb[TE * 18];      // 4.5 KB
    __shared__ __align__(16) float sCss[16 * 64];      // coef[i][e] = CC*y0*s
    __shared__ __align__(16) float sCvv[16 * 64];      // CC/sqrt3*(y1.v)
    __shared__ __align__(16) float sCsv[16 * 64];      // CC*s
    __shared__ __align__(16) float sCvs[48 * 64];      // [(i*3+a)][e] = CC*y0*v
    __shared__ __align__(16) float sAttrT[4 * 64];     // [c][e]
    __shared__ __align__(16) float resSS[64 * 16];     // ss partial (4 KB)
    __shared__ __align__(16) float resSV[64 * 16];     // sv partial (4 KB)

    const int t  = threadIdx.x;
    const int e0 = blockIdx.x * TE;

    // ---------------- phase 1: staging + coef tables ----------------
    ((float4*)sB2)[t] = ((const float4*)b2)[t];        // 256 x float4 = 1024
    for (int idx = t; idx < TE * 18; idx += NTHR) {
        size_t g = (size_t)e0 * 18 + idx;
        sEmb[idx] = (g < (size_t)E * 18) ? eemb[g] : 0.f;
    }
    if (t < TE) {
        int ge = e0 + t;
        float4 a = make_float4(0.f, 0.f, 0.f, 0.f);
        if (ge < E) a = *(const float4*)(eattr + (size_t)ge * 4);
        sAttrT[0 * 64 + t] = a.x; sAttrT[1 * 64 + t] = a.y;
        sAttrT[2 * 64 + t] = a.z; sAttrT[3 * 64 + t] = a.w;
    }
    {   // thread t -> edge e = t>>2, i-quad iq = t&3
        const int e = t >> 2, iq = t & 3;
        const int ge = e0 + e;
        const bool ok = ge < E;
        float y0 = 0.f, y1x = 0.f, y1y = 0.f, y1z = 0.f;
        int src = 0;
        if (ok) {
            float4 a = *(const float4*)(eattr + (size_t)ge * 4);
            y0 = a.x; y1x = a.y; y1y = a.z; y1z = a.w;
            src = esrc[ge];
        }
        const float* xp = nodef + (size_t)src * 64;
        float4 z = make_float4(0.f, 0.f, 0.f, 0.f);
        float4 sv = ok ? *(const float4*)(xp + iq * 4) : z;
        float4 v0 = ok ? *(const float4*)(xp + 16 + iq * 12) : z;
        float4 v1 = ok ? *(const float4*)(xp + 16 + iq * 12 + 4) : z;
        float4 v2 = ok ? *(const float4*)(xp + 16 + iq * 12 + 8) : z;
        const float K3 = CC * 0.57735026918962576f;   // CC/sqrt(3)
        float sarr[4] = { sv.x, sv.y, sv.z, sv.w };
        float varr[12] = { v0.x, v0.y, v0.z, v0.w, v1.x, v1.y, v1.z, v1.w,
                           v2.x, v2.y, v2.z, v2.w };
        #pragma unroll
        for (int j = 0; j < 4; ++j) {
            const int i = iq * 4 + j;
            const float s  = sarr[j];
            const float vx = varr[j * 3 + 0], vy = varr[j * 3 + 1], vz = varr[j * 3 + 2];
            sCss[i * 64 + e] = CC * y0 * s;
            sCvv[i * 64 + e] = K3 * (y1x * vx + y1y * vy + y1z * vz);
            sCsv[i * 64 + e] = CC * s;
            sCvs[(i * 3 + 0) * 64 + e] = CC * y0 * vx;
            sCvs[(i * 3 + 1) * 64 + e] = CC * y0 * vy;
            sCvs[(i * 3 + 2) * 64 + e] = CC * y0 * vz;
        }
    }
    __syncthreads();

    // ---- phase 2: h = silu(emb@W1+b1) -> sAu, 16x16x32 A-frag order ----
    // element (e,k): kk=k>>5, lane=(e&15)+16*((k>>3)&3), slot=k&7; lane^kk swizzle
    {
        const int p = t & 127;         // column pair p -> cols 2p, 2p+1
        const int ehalf = t >> 7;
        const int n0 = 2 * p;
        float w1a[18], w1b[18];
        #pragma unroll
        for (int m = 0; m < 18; ++m) {
            float2 wv = *(const float2*)(W1 + m * 256 + n0);
            w1a[m] = wv.x; w1b[m] = wv.y;
        }
        const float2 bv = *(const float2*)(b1 + n0);
        const int kk = p >> 4;                       // k-iter (0..7)
        const int lhi = 16 * ((p >> 2) & 3);
        const int wsub = p & 3;                      // uint slot within 16B frag
        uint_t* sA32 = (uint_t*)sAu;
        for (int er = 0; er < 32; ++er) {
            const int e = ehalf * 32 + er;
            float a0 = bv.x, a1 = bv.y;
            const float* ep = sEmb + e * 18;
            #pragma unroll
            for (int m = 0; m < 18; ++m) {
                const float em = ep[m];
                a0 = fmaf(em, w1a[m], a0);
                a1 = fmaf(em, w1b[m], a1);
            }
            a0 = a0 / (1.f + __expf(-a0));          // silu
            a1 = a1 / (1.f + __expf(-a1));
            const uint_t pk = (uint_t)f2bf(a0) | ((uint_t)f2bf(a1) << 16);
            const int lane_sw = ((e & 15) + lhi) ^ kk;
            sA32[(((e >> 4) * 8 + kk) * 64 + lane_sw) * 4 + wsub] = pk;
        }
    }
    __syncthreads();

    // ---------------- phase 3: wave = slab; 4 m-tiles per wave ----------------
    const int lane = t & 63;
    const int slab = t >> 6;          // 0:ss 1:vv 2:sv 3:vs
    const int jj   = lane & 15;
    const int q4   = lane >> 4;

    const ushort_t* Bl = W2bf + (size_t)jj * 256 + q4 * 8;  // + nb*256 + kk*32

    float pS[4][4] = {{0.f}};          // ss/vv/sv partials [mt][q]
    float pV[3][4][4] = {{{0.f}}};     // vs partials [a][mtg][q]

    if (slab < 3) {
        // ---- G=4: per kk 4 B loads + 4 A ds_reads -> 16 MFMAs ----
        const float* C = (slab == 0) ? sCss : (slab == 1) ? sCvv : sCsv;
        #pragma unroll 1
        for (int g = 0; g < 4; ++g) {
            f4v acc[4][4];             // [gi][mt], 64 VGPRs
            #pragma unroll
            for (int gi = 0; gi < 4; ++gi) {
                const float bz = sB2[slab * 256 + (4 * g + gi) * 16 + jj];
                #pragma unroll
                for (int mt = 0; mt < 4; ++mt) {
                    f4v z; z[0] = bz; z[1] = bz; z[2] = bz; z[3] = bz;
                    acc[gi][mt] = z;
                }
            }
            #pragma unroll
            for (int kk = 0; kk < 8; ++kk) {
                s8v b[4];
                #pragma unroll
                for (int gi = 0; gi < 4; ++gi)
                    b[gi] = *(const s8v*)(Bl + (size_t)(slab * 256 + (4 * g + gi) * 16) * 256 + kk * 32);
                #pragma unroll
                for (int mt = 0; mt < 4; ++mt) {
                    const s8v a = *(const s8v*)(sAu + ((mt * 8 + kk) * 64 + (lane ^ kk)) * 8);
                    #pragma unroll
                    for (int gi = 0; gi < 4; ++gi)
                        acc[gi][mt] = __builtin_amdgcn_mfma_f32_16x16x32_bf16(a, b[gi], acc[gi][mt], 0, 0, 0);
                }
            }
            #pragma unroll
            for (int gi = 0; gi < 4; ++gi) {
                const int i = 4 * g + gi;
                #pragma unroll
                for (int mt = 0; mt < 4; ++mt) {
                    const int ebase = mt * 16 + q4 * 4;
                    const float4 c = *(const float4*)(C + i * 64 + ebase);
                    pS[mt][0] = fmaf(c.x, acc[gi][mt][0], pS[mt][0]);
                    pS[mt][1] = fmaf(c.y, acc[gi][mt][1], pS[mt][1]);
                    pS[mt][2] = fmaf(c.z, acc[gi][mt][2], pS[mt][2]);
                    pS[mt][3] = fmaf(c.w, acc[gi][mt][3], pS[mt][3]);
                }
            }
        }
        // publish ss / sv partials
        if (slab == 0) {
            #pragma unroll
            for (int mt = 0; mt < 4; ++mt)
                #pragma unroll
                for (int q = 0; q < 4; ++q)
                    resSS[(mt * 16 + q4 * 4 + q) * 16 + jj] = pS[mt][q];
        } else if (slab == 2) {
            #pragma unroll
            for (int mt = 0; mt < 4; ++mt)
                #pragma unroll
                for (int q = 0; q < 4; ++q)
                    resSV[(mt * 16 + q4 * 4 + q) * 16 + jj] = pS[mt][q];
        }
    } else {
        // ---- vs: 2 m-tile-half passes x G=2 (half loop FULLY UNROLLED so
        // pV indices are compile-time constants -> registers, not scratch) ----
        #pragma unroll
        for (int half = 0; half < 2; ++half) {
            #pragma unroll 1
            for (int g = 0; g < 8; ++g) {
                const int i0 = 2 * g, i1 = 2 * g + 1;
                const int nb0 = 3 * 256 + i0 * 16;
                const int nb1 = nb0 + 16;
                f4v acc0[2], acc1[2];   // [mt] for tiles i0, i1
                {
                    const float bz0 = sB2[nb0 + jj];
                    const float bz1 = sB2[nb1 + jj];
                    #pragma unroll
                    for (int mt = 0; mt < 2; ++mt) {
                        f4v z0; z0[0] = bz0; z0[1] = bz0; z0[2] = bz0; z0[3] = bz0;
                        f4v z1; z1[0] = bz1; z1[1] = bz1; z1[2] = bz1; z1[3] = bz1;
                        acc0[mt] = z0; acc1[mt] = z1;
                    }
                }
                #pragma unroll
                for (int kk = 0; kk < 8; ++kk) {
                    const s8v b0 = *(const s8v*)(Bl + (size_t)nb0 * 256 + kk * 32);
                    const s8v b1 = *(const s8v*)(Bl + (size_t)nb1 * 256 + kk * 32);
                    #pragma unroll
                    for (int mt = 0; mt < 2; ++mt) {
                        const int mtg = half * 2 + mt;
                        const s8v a = *(const s8v*)(sAu + ((mtg * 8 + kk) * 64 + (lane ^ kk)) * 8);
                        acc0[mt] = __builtin_amdgcn_mfma_f32_16x16x32_bf16(a, b0, acc0[mt], 0, 0, 0);
                        acc1[mt] = __builtin_amdgcn_mfma_f32_16x16x32_bf16(a, b1, acc1[mt], 0, 0, 0);
                    }
                }
                #pragma unroll
                for (int mt = 0; mt < 2; ++mt) {
                    const int mtg = half * 2 + mt;
                    const int ebase = mtg * 16 + q4 * 4;
                    #pragma unroll
                    for (int a = 0; a < 3; ++a) {
                        const float4 c0 = *(const float4*)(sCvs + (i0 * 3 + a) * 64 + ebase);
                        const float4 c1 = *(const float4*)(sCvs + (i1 * 3 + a) * 64 + ebase);
                        pV[a][mtg][0] += c0.x * acc0[mt][0] + c1.x * acc1[mt][0];
                        pV[a][mtg][1] += c0.y * acc0[mt][1] + c1.y * acc1[mt][1];
                        pV[a][mtg][2] += c0.z * acc0[mt][2] + c1.z * acc1[mt][2];
                        pV[a][mtg][3] += c0.w * acc0[mt][3] + c1.w * acc1[mt][3];
                    }
                }
            }
        }
    }
    __syncthreads();

    // ---------------- combine + store to F (bf16) ----------------
    if (slab == 1) {          // out_s = resSS(ss) + vv partial
        #pragma unroll
        for (int mt = 0; mt < 4; ++mt) {
            #pragma unroll
            for (int q = 0; q < 4; ++q) {
                const int e = mt * 16 + q4 * 4 + q;
                const int ge = e0 + e;
                if (ge < E) F[(size_t)ge * 64 + jj] = f2bf(resSS[e * 16 + jj] + pS[mt][q]);
            }
        }
    } else if (slab == 3) {   // out_v[a] = y1[a]*resSV(sv) + vs partial
        #pragma unroll
        for (int mt = 0; mt < 4; ++mt) {
            #pragma unroll
            for (int q = 0; q < 4; ++q) {
                const int e = mt * 16 + q4 * 4 + q;
                const int ge = e0 + e;
                const float sv = resSV[e * 16 + jj];
                if (ge < E) {
                    #pragma unroll
                    for (int a = 0; a < 3; ++a)
                        F[(size_t)ge * 64 + 16 + jj * 3 + a] =
                            f2bf(fmaf(sAttrT[(1 + a) * 64 + e], sv, pV[a][mt][q]));
                }
            }
        }
    }
}

extern "C" void kernel_launch(void* const* d_in, const int* in_sizes, int n_in,
                              void* d_out, int out_size, void* d_ws, size_t ws_size,
                              hipStream_t stream)
{
    const float* node_features = (const float*)d_in[0];
    const float* edge_attr     = (const float*)d_in[1];
    const float* edge_emb      = (const float*)d_in[2];
    const float* W1            = (const float*)d_in[3];
    const float* b1            = (const float*)d_in[4];
    const float* W2            = (const float*)d_in[5];
    const float* b2            = (const float*)d_in[6];
    const int*   edge_src      = (const int*)d_in[7];
    const int*   edge_dst      = (const int*)d_in[8];
    float*       out           = (float*)d_out;

    const int E = in_sizes[7];
    const int N = out_size / 64;
    const float num_neigh = (float)E / (float)N;
    const float CC = 0.17677669529663689f / sqrtf(num_neigh);

    // ---- workspace layout ----
    char* ws = (char*)d_ws;
    size_t off = 0;
    auto alloc = [&](size_t bytes) { char* p = ws + off; off = (off + bytes + 255) & ~(size_t)255; return p; };
    ushort_t* W2bf   = (ushort_t*)alloc((size_t)1024 * 256 * 2);
    int*      counts = (int*)alloc((size_t)2 * N * 4);    // counts[N] + cursor[N]
    int*      cursor = counts + N;
    int*      offs   = (int*)alloc((size_t)(N + 1) * 4);
    int*      elist  = (int*)alloc((size_t)E * 4);
    ushort_t* F      = (ushort_t*)alloc((size_t)E * 64 * 2);
    (void)ws_size;

    hipMemsetAsync(counts, 0, (size_t)2 * N * 4, stream);

    const int histBlocks = (E + 255) / 256;
    prep_kernel<<<256 + histBlocks, 256, 0, stream>>>(W2, W2bf, edge_dst, counts, E);
    scan_kernel<<<1, 1024, 0, stream>>>(counts, offs, N);
    fill_kernel<<<histBlocks, 256, 0, stream>>>(edge_dst, offs, cursor, elist, E);

    const int blocks = (E + TE - 1) / TE;
    nequip_mfma<<<blocks, NTHR, 0, stream>>>(
        node_features, edge_attr, edge_emb, W1, b1, W2bf, b2,
        edge_src, F, E, CC);

    gather_kernel<<<(N + 3) / 4, 256, 0, stream>>>(F, offs, elist, out, N);
}

// Round 16
// 341.693 us; speedup vs baseline: 1.0464x; 1.0464x over previous
//
#include <hip/hip_runtime.h>
#include <math.h>

// ---------------------------------------------------------------------------
// NequIP fused, round 15: revert to R13's G=2 main (measured best, 258us);
// fuse the CSR fill into main's phase 1.
//
// R14 post-mortem: G=4 halved A ds_reads with zero gain -> phase 3 is no
// longer LDS-bound; main plateaued ~258us. Attack the ~93us serial aux chain:
// fill (160k contended atomics, ~25-30us standalone) has exactly main's work
// partition (64 edges/block) and main has ~50% idle issue -> fuse it into
// phase 1. Chain: memset -> prep(conv+hist) -> scan -> main(+fill) -> gather.
// ---------------------------------------------------------------------------

typedef __attribute__((ext_vector_type(8))) short s8v;    // 8 x bf16 (4 VGPR)
typedef __attribute__((ext_vector_type(4))) float f4v;    // 16x16 acc (4 f32)
typedef unsigned short ushort_t;
typedef unsigned int uint_t;

#define NTHR 256
#define TE 64

__device__ __forceinline__ ushort_t f2bf(float x) {
    uint_t u = __float_as_uint(x);
    u += 0x7fffu + ((u >> 16) & 1u);   // round-to-nearest-even
    return (ushort_t)(u >> 16);
}
__device__ __forceinline__ float bf2f(ushort_t v) {
    return __uint_as_float((uint_t)v << 16);
}

// blocks [0,256): W2 [256][1024] fp32 -> W2bf [1024][256] bf16 (transposed).
// blocks [256,...): histogram of edge_dst into counts.
__global__ void prep_kernel(const float* __restrict__ W2, ushort_t* __restrict__ W2bf,
                            const int* __restrict__ edst, int* __restrict__ counts, int E) {
    if (blockIdx.x < 256) {
        int idx = blockIdx.x * 256 + threadIdx.x;      // 65536 threads, 4 k each
        int n  = idx & 1023;
        int k4 = (idx >> 10) << 2;
        uint_t lo = (uint_t)f2bf(W2[(size_t)(k4 + 0) * 1024 + n]) |
                    ((uint_t)f2bf(W2[(size_t)(k4 + 1) * 1024 + n]) << 16);
        uint_t hi = (uint_t)f2bf(W2[(size_t)(k4 + 2) * 1024 + n]) |
                    ((uint_t)f2bf(W2[(size_t)(k4 + 3) * 1024 + n]) << 16);
        ((uint2*)W2bf)[(n * 256 + k4) >> 2] = make_uint2(lo, hi);
    } else {
        int i = (blockIdx.x - 256) * 256 + threadIdx.x;
        if (i < E) atomicAdd(&counts[edst[i]], 1);
    }
}

// 1 block, 1024 threads: exclusive scan of counts[N] -> offsets[N+1]
__global__ __launch_bounds__(1024)
void scan_kernel(const int* __restrict__ counts, int* __restrict__ offsets, int N) {
    __shared__ int sdata[1024];
    const int t = threadIdx.x;
    const int C = (N + 1023) / 1024;
    const int lo = t * C;
    const int hi = min(lo + C, N);
    int sum = 0;
    for (int i = lo; i < hi; ++i) sum += counts[i];
    sdata[t] = sum;
    __syncthreads();
    for (int s = 1; s < 1024; s <<= 1) {
        int v = (t >= s) ? sdata[t - s] : 0;
        __syncthreads();
        sdata[t] += v;
        __syncthreads();
    }
    int run = sdata[t] - sum;
    for (int i = lo; i < hi; ++i) { offsets[i] = run; run += counts[i]; }
    if (t == 1023) offsets[N] = run;
}

// ---------------- gather: one wave per node; F is bf16 ----------------
__global__ __launch_bounds__(256)
void gather_kernel(const ushort_t* __restrict__ F,
                   const int* __restrict__ offsets,
                   const int* __restrict__ elist,
                   float* __restrict__ out, int N) {
    const int lane = threadIdx.x & 63;
    const int node = (blockIdx.x * 256 + threadIdx.x) >> 6;
    if (node >= N) return;
    const int base = offsets[node];
    const int end  = offsets[node + 1];
    float acc = 0.f;
    for (int j0 = base; j0 < end; j0 += 64) {
        const int rem = min(64, end - j0);
        int myeid = (lane < rem) ? elist[j0 + lane] : 0;
        int j = 0;
        for (; j + 4 <= rem; j += 4) {
            const int a0 = __shfl(myeid, j    );
            const int a1 = __shfl(myeid, j + 1);
            const int a2 = __shfl(myeid, j + 2);
            const int a3 = __shfl(myeid, j + 3);
            const float r0 = bf2f(F[(size_t)a0 * 64 + lane]);
            const float r1 = bf2f(F[(size_t)a1 * 64 + lane]);
            const float r2 = bf2f(F[(size_t)a2 * 64 + lane]);
            const float r3 = bf2f(F[(size_t)a3 * 64 + lane]);
            acc += (r0 + r1) + (r2 + r3);
        }
        for (; j < rem; ++j) {
            const int a = __shfl(myeid, j);
            acc += bf2f(F[(size_t)a * 64 + lane]);
        }
    }
    out[(size_t)node * 64 + lane] = acc;
}

// ---------------- main fused edge kernel (256 thr, 4 waves) ----------------
// Also performs the CSR fill for its own 64 edges (fused from fill_kernel).
__global__ __launch_bounds__(NTHR, 2)
void nequip_mfma(const float* __restrict__ nodef,
                 const float* __restrict__ eattr,
                 const float* __restrict__ eemb,
                 const float* __restrict__ W1,
                 const float* __restrict__ b1,
                 const ushort_t* __restrict__ W2bf,
                 const float* __restrict__ b2,
                 const int* __restrict__ esrc,
                 const int* __restrict__ edst,
                 const int* __restrict__ offs,
                 int* __restrict__ cursor,
                 int* __restrict__ elist,
                 ushort_t* __restrict__ F,
                 int E, float CC)
{
    __shared__ __align__(16) ushort_t sAu[TE * 256];   // 32 KB h bf16, A-frag order
    __shared__ __align__(16) float sB2[1024];          // 4 KB
    __shared__ __align__(16) float sEmb[TE * 18];      // 4.5 KB
    __shared__ __align__(16) float sCss[16 * 64];      // coef[i][e] = CC*y0*s
    __shared__ __align__(16) float sCvv[16 * 64];      // CC/sqrt3*(y1.v)
    __shared__ __align__(16) float sCsv[16 * 64];      // CC*s
    __shared__ __align__(16) float sCvs[48 * 64];      // [(i*3+a)][e] = CC*y0*v
    __shared__ __align__(16) float sAttrT[4 * 64];     // [c][e]
    __shared__ __align__(16) float resSS[64 * 16];     // ss partial (4 KB)
    __shared__ __align__(16) float resSV[64 * 16];     // sv partial (4 KB)

    const int t  = threadIdx.x;
    const int e0 = blockIdx.x * TE;

    // ---------------- phase 1: staging + coef tables + CSR fill ----------------
    ((float4*)sB2)[t] = ((const float4*)b2)[t];        // 256 x float4 = 1024
    for (int idx = t; idx < TE * 18; idx += NTHR) {
        size_t g = (size_t)e0 * 18 + idx;
        sEmb[idx] = (g < (size_t)E * 18) ? eemb[g] : 0.f;
    }
    if (t < TE) {
        int ge = e0 + t;
        float4 a = make_float4(0.f, 0.f, 0.f, 0.f);
        if (ge < E) {
            a = *(const float4*)(eattr + (size_t)ge * 4);
            // fused CSR fill for this block's edges
            const int d = edst[ge];
            const int pos = offs[d] + atomicAdd(&cursor[d], 1);
            elist[pos] = ge;
        }
        sAttrT[0 * 64 + t] = a.x; sAttrT[1 * 64 + t] = a.y;
        sAttrT[2 * 64 + t] = a.z; sAttrT[3 * 64 + t] = a.w;
    }
    {   // thread t -> edge e = t>>2, i-quad iq = t&3
        const int e = t >> 2, iq = t & 3;
        const int ge = e0 + e;
        const bool ok = ge < E;
        float y0 = 0.f, y1x = 0.f, y1y = 0.f, y1z = 0.f;
        int src = 0;
        if (ok) {
            float4 a = *(const float4*)(eattr + (size_t)ge * 4);
            y0 = a.x; y1x = a.y; y1y = a.z; y1z = a.w;
            src = esrc[ge];
        }
        const float* xp = nodef + (size_t)src * 64;
        float4 z = make_float4(0.f, 0.f, 0.f, 0.f);
        float4 sv = ok ? *(const float4*)(xp + iq * 4) : z;
        float4 v0 = ok ? *(const float4*)(xp + 16 + iq * 12) : z;
        float4 v1 = ok ? *(const float4*)(xp + 16 + iq * 12 + 4) : z;
        float4 v2 = ok ? *(const float4*)(xp + 16 + iq * 12 + 8) : z;
        const float K3 = CC * 0.57735026918962576f;   // CC/sqrt(3)
        float sarr[4] = { sv.x, sv.y, sv.z, sv.w };
        float varr[12] = { v0.x, v0.y, v0.z, v0.w, v1.x, v1.y, v1.z, v1.w,
                           v2.x, v2.y, v2.z, v2.w };
        #pragma unroll
        for (int j = 0; j < 4; ++j) {
            const int i = iq * 4 + j;
            const float s  = sarr[j];
            const float vx = varr[j * 3 + 0], vy = varr[j * 3 + 1], vz = varr[j * 3 + 2];
            sCss[i * 64 + e] = CC * y0 * s;
            sCvv[i * 64 + e] = K3 * (y1x * vx + y1y * vy + y1z * vz);
            sCsv[i * 64 + e] = CC * s;
            sCvs[(i * 3 + 0) * 64 + e] = CC * y0 * vx;
            sCvs[(i * 3 + 1) * 64 + e] = CC * y0 * vy;
            sCvs[(i * 3 + 2) * 64 + e] = CC * y0 * vz;
        }
    }
    __syncthreads();

    // ---- phase 2: h = silu(emb@W1+b1) -> sAu, 16x16x32 A-frag order ----
    // element (e,k): kk=k>>5, lane=(e&15)+16*((k>>3)&3), slot=k&7; lane^kk swizzle
    {
        const int p = t & 127;         // column pair p -> cols 2p, 2p+1
        const int ehalf = t >> 7;
        const int n0 = 2 * p;
        float w1a[18], w1b[18];
        #pragma unroll
        for (int m = 0; m < 18; ++m) {
            float2 wv = *(const float2*)(W1 + m * 256 + n0);
            w1a[m] = wv.x; w1b[m] = wv.y;
        }
        const float2 bv = *(const float2*)(b1 + n0);
        const int kk = p >> 4;                       // k-iter (0..7)
        const int lhi = 16 * ((p >> 2) & 3);
        const int wsub = p & 3;                      // uint slot within 16B frag
        uint_t* sA32 = (uint_t*)sAu;
        for (int er = 0; er < 32; ++er) {
            const int e = ehalf * 32 + er;
            float a0 = bv.x, a1 = bv.y;
            const float* ep = sEmb + e * 18;
            #pragma unroll
            for (int m = 0; m < 18; ++m) {
                const float em = ep[m];
                a0 = fmaf(em, w1a[m], a0);
                a1 = fmaf(em, w1b[m], a1);
            }
            a0 = a0 / (1.f + __expf(-a0));          // silu
            a1 = a1 / (1.f + __expf(-a1));
            const uint_t pk = (uint_t)f2bf(a0) | ((uint_t)f2bf(a1) << 16);
            const int lane_sw = ((e & 15) + lhi) ^ kk;
            sA32[(((e >> 4) * 8 + kk) * 64 + lane_sw) * 4 + wsub] = pk;
        }
    }
    __syncthreads();

    // ---------------- phase 3: wave = slab; 4 m-tiles per wave ----------------
    const int lane = t & 63;
    const int slab = t >> 6;          // 0:ss 1:vv 2:sv 3:vs
    const int jj   = lane & 15;
    const int q4   = lane >> 4;

    const ushort_t* Bl = W2bf + (size_t)jj * 256 + q4 * 8;  // + nb*256 + kk*32

    float pS[4][4] = {{0.f}};          // ss/vv/sv partials [mt][q]
    float pV[3][4][4] = {{{0.f}}};     // vs partials [a][mtg][q]

    if (slab < 3) {
        // ---- G=2: per kk 4 A ds_reads (shared) + 2 B loads -> 8 MFMAs ----
        const float* C = (slab == 0) ? sCss : (slab == 1) ? sCvv : sCsv;
        #pragma unroll 1
        for (int g = 0; g < 8; ++g) {
            const int nb0 = slab * 256 + (2 * g) * 16;
            const int nb1 = nb0 + 16;
            f4v accA[4], accB[4];
            {
                const float bz0 = sB2[nb0 + jj];
                const float bz1 = sB2[nb1 + jj];
                #pragma unroll
                for (int mt = 0; mt < 4; ++mt) {
                    f4v zA; zA[0] = bz0; zA[1] = bz0; zA[2] = bz0; zA[3] = bz0;
                    f4v zB; zB[0] = bz1; zB[1] = bz1; zB[2] = bz1; zB[3] = bz1;
                    accA[mt] = zA; accB[mt] = zB;
                }
            }
            #pragma unroll
            for (int kk = 0; kk < 8; ++kk) {
                const s8v b0 = *(const s8v*)(Bl + (size_t)nb0 * 256 + kk * 32);
                const s8v b1 = *(const s8v*)(Bl + (size_t)nb1 * 256 + kk * 32);
                #pragma unroll
                for (int mt = 0; mt < 4; ++mt) {
                    const s8v a = *(const s8v*)(sAu + ((mt * 8 + kk) * 64 + (lane ^ kk)) * 8);
                    accA[mt] = __builtin_amdgcn_mfma_f32_16x16x32_bf16(a, b0, accA[mt], 0, 0, 0);
                    accB[mt] = __builtin_amdgcn_mfma_f32_16x16x32_bf16(a, b1, accB[mt], 0, 0, 0);
                }
            }
            const int i0 = 2 * g, i1 = 2 * g + 1;
            #pragma unroll
            for (int mt = 0; mt < 4; ++mt) {
                const int ebase = mt * 16 + q4 * 4;
                const float4 c0 = *(const float4*)(C + i0 * 64 + ebase);
                const float4 c1 = *(const float4*)(C + i1 * 64 + ebase);
                pS[mt][0] += c0.x * accA[mt][0] + c1.x * accB[mt][0];
                pS[mt][1] += c0.y * accA[mt][1] + c1.y * accB[mt][1];
                pS[mt][2] += c0.z * accA[mt][2] + c1.z * accB[mt][2];
                pS[mt][3] += c0.w * accA[mt][3] + c1.w * accB[mt][3];
            }
        }
        // publish ss / sv partials
        if (slab == 0) {
            #pragma unroll
            for (int mt = 0; mt < 4; ++mt)
                #pragma unroll
                for (int q = 0; q < 4; ++q)
                    resSS[(mt * 16 + q4 * 4 + q) * 16 + jj] = pS[mt][q];
        } else if (slab == 2) {
            #pragma unroll
            for (int mt = 0; mt < 4; ++mt)
                #pragma unroll
                for (int q = 0; q < 4; ++q)
                    resSV[(mt * 16 + q4 * 4 + q) * 16 + jj] = pS[mt][q];
        }
    } else {
        // ---- vs: 2 m-tile-half passes x G=2 (half loop FULLY UNROLLED so
        // pV indices are compile-time constants -> registers, not scratch) ----
        #pragma unroll
        for (int half = 0; half < 2; ++half) {
            #pragma unroll 1
            for (int g = 0; g < 8; ++g) {
                const int i0 = 2 * g, i1 = 2 * g + 1;
                const int nb0 = 3 * 256 + i0 * 16;
                const int nb1 = nb0 + 16;
                f4v acc0[2], acc1[2];   // [mt] for tiles i0, i1
                {
                    const float bz0 = sB2[nb0 + jj];
                    const float bz1 = sB2[nb1 + jj];
                    #pragma unroll
                    for (int mt = 0; mt < 2; ++mt) {
                        f4v z0; z0[0] = bz0; z0[1] = bz0; z0[2] = bz0; z0[3] = bz0;
                        f4v z1; z1[0] = bz1; z1[1] = bz1; z1[2] = bz1; z1[3] = bz1;
                        acc0[mt] = z0; acc1[mt] = z1;
                    }
                }
                #pragma unroll
                for (int kk = 0; kk < 8; ++kk) {
                    const s8v b0 = *(const s8v*)(Bl + (size_t)nb0 * 256 + kk * 32);
                    const s8v b1 = *(const s8v*)(Bl + (size_t)nb1 * 256 + kk * 32);
                    #pragma unroll
                    for (int mt = 0; mt < 2; ++mt) {
                        const int mtg = half * 2 + mt;
                        const s8v a = *(const s8v*)(sAu + ((mtg * 8 + kk) * 64 + (lane ^ kk)) * 8);
                        acc0[mt] = __builtin_amdgcn_mfma_f32_16x16x32_bf16(a, b0, acc0[mt], 0, 0, 0);
                        acc1[mt] = __builtin_amdgcn_mfma_f32_16x16x32_bf16(a, b1, acc1[mt], 0, 0, 0);
                    }
                }
                #pragma unroll
                for (int mt = 0; mt < 2; ++mt) {
                    const int mtg = half * 2 + mt;
                    const int ebase = mtg * 16 + q4 * 4;
                    #pragma unroll
                    for (int a = 0; a < 3; ++a) {
                        const float4 c0 = *(const float4*)(sCvs + (i0 * 3 + a) * 64 + ebase);
                        const float4 c1 = *(const float4*)(sCvs + (i1 * 3 + a) * 64 + ebase);
                        pV[a][mtg][0] += c0.x * acc0[mt][0] + c1.x * acc1[mt][0];
                        pV[a][mtg][1] += c0.y * acc0[mt][1] + c1.y * acc1[mt][1];
                        pV[a][mtg][2] += c0.z * acc0[mt][2] + c1.z * acc1[mt][2];
                        pV[a][mtg][3] += c0.w * acc0[mt][3] + c1.w * acc1[mt][3];
                    }
                }
            }
        }
    }
    __syncthreads();

    // ---------------- combine + store to F (bf16) ----------------
    if (slab == 1) {          // out_s = resSS(ss) + vv partial
        #pragma unroll
        for (int mt = 0; mt < 4; ++mt) {
            #pragma unroll
            for (int q = 0; q < 4; ++q) {
                const int e = mt * 16 + q4 * 4 + q;
                const int ge = e0 + e;
                if (ge < E) F[(size_t)ge * 64 + jj] = f2bf(resSS[e * 16 + jj] + pS[mt][q]);
            }
        }
    } else if (slab == 3) {   // out_v[a] = y1[a]*resSV(sv) + vs partial
        #pragma unroll
        for (int mt = 0; mt < 4; ++mt) {
            #pragma unroll
            for (int q = 0; q < 4; ++q) {
                const int e = mt * 16 + q4 * 4 + q;
                const int ge = e0 + e;
                const float sv = resSV[e * 16 + jj];
                if (ge < E) {
                    #pragma unroll
                    for (int a = 0; a < 3; ++a)
                        F[(size_t)ge * 64 + 16 + jj * 3 + a] =
                            f2bf(fmaf(sAttrT[(1 + a) * 64 + e], sv, pV[a][mt][q]));
                }
            }
        }
    }
}

extern "C" void kernel_launch(void* const* d_in, const int* in_sizes, int n_in,
                              void* d_out, int out_size, void* d_ws, size_t ws_size,
                              hipStream_t stream)
{
    const float* node_features = (const float*)d_in[0];
    const float* edge_attr     = (const float*)d_in[1];
    const float* edge_emb      = (const float*)d_in[2];
    const float* W1            = (const float*)d_in[3];
    const float* b1            = (const float*)d_in[4];
    const float* W2            = (const float*)d_in[5];
    const float* b2            = (const float*)d_in[6];
    const int*   edge_src      = (const int*)d_in[7];
    const int*   edge_dst      = (const int*)d_in[8];
    float*       out           = (float*)d_out;

    const int E = in_sizes[7];
    const int N = out_size / 64;
    const float num_neigh = (float)E / (float)N;
    const float CC = 0.17677669529663689f / sqrtf(num_neigh);

    // ---- workspace layout ----
    char* ws = (char*)d_ws;
    size_t off = 0;
    auto alloc = [&](size_t bytes) { char* p = ws + off; off = (off + bytes + 255) & ~(size_t)255; return p; };
    ushort_t* W2bf   = (ushort_t*)alloc((size_t)1024 * 256 * 2);
    int*      counts = (int*)alloc((size_t)2 * N * 4);    // counts[N] + cursor[N]
    int*      cursor = counts + N;
    int*      offs   = (int*)alloc((size_t)(N + 1) * 4);
    int*      elist  = (int*)alloc((size_t)E * 4);
    ushort_t* F      = (ushort_t*)alloc((size_t)E * 64 * 2);
    (void)ws_size;

    hipMemsetAsync(counts, 0, (size_t)2 * N * 4, stream);

    const int histBlocks = (E + 255) / 256;
    prep_kernel<<<256 + histBlocks, 256, 0, stream>>>(W2, W2bf, edge_dst, counts, E);
    scan_kernel<<<1, 1024, 0, stream>>>(counts, offs, N);

    const int blocks = (E + TE - 1) / TE;
    nequip_mfma<<<blocks, NTHR, 0, stream>>>(
        node_features, edge_attr, edge_emb, W1, b1, W2bf, b2,
        edge_src, edge_dst, offs, cursor, elist, F, E, CC);

    gather_kernel<<<(N + 3) / 4, 256, 0, stream>>>(F, offs, elist, out, N);
}